// Round 12
// baseline (263.413 us; speedup 1.0000x reference)
//
#include <hip/hip_runtime.h>
#include <hip/hip_bf16.h>

// B=8, S=2048, E=128, H=8, D=16;  BH=64;  N=B*S=16384

typedef __attribute__((ext_vector_type(4))) float f32x4;
typedef __attribute__((ext_vector_type(8))) short bf16x8;
typedef __attribute__((ext_vector_type(8))) _Float16 half8;
typedef __attribute__((ext_vector_type(2))) int int2v;
typedef __attribute__((ext_vector_type(4))) int int4v;
typedef __attribute__((ext_vector_type(4))) short short4v;

static __device__ inline float bf2f(short s) {
  union { unsigned u; float f; } x; x.u = ((unsigned)(unsigned short)s) << 16;
  return x.f;
}
static __device__ inline bf16x8 maskfrag(bf16x8 v, int msk) {
  union { bf16x8 s; int4v i; } u; u.s = v;
  u.i[0] &= msk; u.i[1] &= msk; u.i[2] &= msk; u.i[3] &= msk;
  return u.s;
}

// Raw workgroup barrier that drains ONLY lgkmcnt (LDS) — global stores
// stay in flight across it. All cross-wave deps in attn_kernel are LDS.
#define SYNCL()                                          \
  do {                                                   \
    __builtin_amdgcn_sched_barrier(0);                   \
    asm volatile("s_waitcnt lgkmcnt(0)" ::: "memory");   \
    __builtin_amdgcn_s_barrier();                        \
    __builtin_amdgcn_sched_barrier(0);                   \
  } while (0)

// ---------------- W fp32 -> f16 (one-time) ----------------
__global__ __launch_bounds__(256) void cvt_w_kernel(const float* __restrict__ Wq,
                                                    const float* __restrict__ Wk,
                                                    const float* __restrict__ Wv,
                                                    const float* __restrict__ Wo,
                                                    _Float16* __restrict__ out) {
  int i = blockIdx.x * 256 + threadIdx.x;      // grid 64 -> 16384
  out[i]             = (_Float16)Wq[i];
  out[16384 + i]     = (_Float16)Wk[i];
  out[2 * 16384 + i] = (_Float16)Wv[i];
  out[3 * 16384 + i] = (_Float16)Wo[i];
}

// ---------------- MFMA projection: out = (x @ W^T + b) * scale ----------------
// MODE 0: bf16 [BH][S][16] (Q/K)   MODE 1: bf16 [BH][16][S] (V^T)   MODE 2: f32 [N][128]
template <int MODE>
__global__ __launch_bounds__(256) void proj16(const float* __restrict__ x,
                                              const _Float16* __restrict__ Wh,
                                              const float* __restrict__ bias,
                                              void* __restrict__ out, float scale) {
  const int t = threadIdx.x;
  const int wv = t >> 6, lane = t & 63;
  const int col = lane & 15, g4 = lane >> 4;
  const int r0 = blockIdx.x * 64 + wv * 16;

  f32x4 acc[8];
  #pragma unroll
  for (int et = 0; et < 8; ++et) {
    float bv = bias[et * 16 + col];
    acc[et] = (f32x4){bv, bv, bv, bv};
  }
  #pragma unroll
  for (int ck = 0; ck < 4; ++ck) {
    const float* xp = x + (size_t)(r0 + col) * 128 + ck * 32 + g4 * 8;
    f32x4 x0 = *(const f32x4*)xp;
    f32x4 x1 = *(const f32x4*)(xp + 4);
    half8 a;
    #pragma unroll
    for (int j = 0; j < 4; ++j) { a[j] = (_Float16)x0[j]; a[j + 4] = (_Float16)x1[j]; }
    #pragma unroll
    for (int et = 0; et < 8; ++et) {
      half8 b = *(const half8*)(Wh + (size_t)(et * 16 + col) * 128 + ck * 32 + g4 * 8);
      acc[et] = __builtin_amdgcn_mfma_f32_16x16x32_f16(a, b, acc[et], 0, 0, 0);
    }
  }
  #pragma unroll
  for (int et = 0; et < 8; ++et) {
    #pragma unroll
    for (int rr = 0; rr < 4; ++rr) {
      int n = r0 + 4 * g4 + rr;
      float v = acc[et][rr] * scale;
      if (MODE == 2) {
        ((float*)out)[(size_t)n * 128 + et * 16 + col] = v;
      } else {
        int bb = n >> 11, s = n & 2047;
        size_t idx = (MODE == 0)
            ? ((size_t)(bb * 8 + et) * 2048 + s) * 16 + col
            : ((size_t)(bb * 8 + et) * 16 + col) * 2048 + s;
        ((__hip_bfloat16*)out)[idx] = __float2bfloat16(v);
      }
    }
  }
}

// ---------------- fused attention (persistent, 4 q-tiles per block) ----------
// grid: 64 heads * 32 groups; block 256 (4 waves); 4 tiles x 16 q-rows each.
// Qg,Kg: [BH][S][16] bf16 (Q pre-scaled 0.25*log2e); Vt: [BH][16][S] bf16.
//
// R12 A/B (single variable vs R11): Phase-C stores nt -> PLAIN CACHED.
// Store-flavor x structure matrix so far: cached+loads=342/294 (R7/R9),
// nt+anything=244-260 (R6/R8/R11), sc1=294 (R10). The untested cell is
// cached+ZERO-loads — which is exactly the fill-kernel configuration that
// sustains 6.5 TB/s (plain cached dwordx4, FETCH~0). R11's prologue already
// removed every load from the store window (K/V/Q all in 208 VGPRs), so the
// earlier cached failures' load-interaction explanations don't apply here.
__global__ __launch_bounds__(256, 2) void attn_kernel(const __hip_bfloat16* __restrict__ Qg,
                                                      const __hip_bfloat16* __restrict__ Kg,
                                                      const __hip_bfloat16* __restrict__ Vt,
                                                      float* __restrict__ attn_out,
                                                      float* __restrict__ ctx_out) {
  __shared__ short sE[16][2056];     // bf16 2^(s'); +8 pad
  __shared__ float wsum[4][16];
  __shared__ float inv_s[16];
  __shared__ float psum[4][16][16];
  const int t = threadIdx.x;
  const int wv = t >> 6, lane = t & 63;
  const int col = lane & 15, g4 = lane >> 4;
  const int bh = blockIdx.x >> 5;
  const int qg = (blockIdx.x & 31) * 64;
  const int msk = (lane < 32) ? -1 : 0;

  // ---- Prologue: every global load of the block's lifetime, before any store.
  bf16x8 kf[32], vf[16], qf[4];
  {
    const __hip_bfloat16* kp =
        Kg + ((size_t)bh * 2048 + (size_t)(wv * 32) * 16 + col) * 16 + (g4 & 1) * 8;
    #pragma unroll
    for (int j = 0; j < 32; ++j) kf[j] = *(const bf16x8*)(kp + j * 256);
    const __hip_bfloat16* vp =
        Vt + ((size_t)bh * 16 + col) * 2048 + (size_t)(wv * 16) * 32 + 8 * g4;
    #pragma unroll
    for (int j = 0; j < 16; ++j) vf[j] = *(const bf16x8*)(vp + j * 32);
    #pragma unroll
    for (int tt = 0; tt < 4; ++tt)
      qf[tt] = *(const bf16x8*)(Qg +
                (((size_t)bh * 2048 + qg + tt * 16 + col) * 16 + (g4 & 1) * 8));
    // K is the MFMA A-operand: k-chunks >=16 (lanes>=32) must be zero (D=16).
    #pragma unroll
    for (int j = 0; j < 32; ++j) kf[j] = maskfrag(kf[j], msk);
  }

  #pragma unroll
  for (int tile = 0; tile < 4; ++tile) {
    const int q0 = qg + tile * 16;
    const bf16x8 qfrag = qf[tile];

    // ---- Phase A: S' = Q'K^T (base-2), e = exp2(S') -> LDS + sums. Pure reg+LDS.
    float rsum = 0.f;
    #pragma unroll
    for (int ib = 0; ib < 8; ++ib) {
      #pragma unroll
      for (int r = 0; r < 4; ++r) {
        int kt = wv * 32 + ib * 4 + r;
        f32x4 c = __builtin_amdgcn_mfma_f32_16x16x32_bf16(kf[ib * 4 + r], qfrag,
                                                          (f32x4){0.f, 0.f, 0.f, 0.f},
                                                          0, 0, 0);
        float e0 = exp2f(c[0]), e1 = exp2f(c[1]);
        float e2 = exp2f(c[2]), e3 = exp2f(c[3]);
        rsum += (e0 + e1) + (e2 + e3);
        union { __hip_bfloat162 h; int u; } p0, p1;
        p0.h = __float22bfloat162_rn(make_float2(e0, e1));
        p1.h = __float22bfloat162_rn(make_float2(e2, e3));
        int2v pk = {p0.u, p1.u};
        *(int2v*)&sE[col][kt * 16 + 4 * g4] = pk;
      }
    }
    rsum += __shfl_xor(rsum, 16);
    rsum += __shfl_xor(rsum, 32);
    if (lane < 16) wsum[wv][lane] = rsum;
    SYNCL();
    if (t < 16) inv_s[t] = 1.f / (wsum[0][t] + wsum[1][t] + wsum[2][t] + wsum[3][t]);
    SYNCL();

    // ---- Phase D: ctx = P V (waves split K; V from registers; dual acc) ----
    {
      const int kbb = (wv * 16) * 32 + 8 * g4;
      f32x4 acc0 = {0.f, 0.f, 0.f, 0.f}, acc1 = {0.f, 0.f, 0.f, 0.f};
      #pragma unroll
      for (int ib = 0; ib < 4; ++ib) {
        int kb = kbb + ib * 128;
        bf16x8 a0 = *(const bf16x8*)&sE[col][kb];
        acc0 = __builtin_amdgcn_mfma_f32_16x16x32_bf16(a0, vf[ib * 4 + 0], acc0, 0, 0, 0);
        bf16x8 a1 = *(const bf16x8*)&sE[col][kb + 32];
        acc1 = __builtin_amdgcn_mfma_f32_16x16x32_bf16(a1, vf[ib * 4 + 1], acc1, 0, 0, 0);
        bf16x8 a2 = *(const bf16x8*)&sE[col][kb + 64];
        acc0 = __builtin_amdgcn_mfma_f32_16x16x32_bf16(a2, vf[ib * 4 + 2], acc0, 0, 0, 0);
        bf16x8 a3 = *(const bf16x8*)&sE[col][kb + 96];
        acc1 = __builtin_amdgcn_mfma_f32_16x16x32_bf16(a3, vf[ib * 4 + 3], acc1, 0, 0, 0);
      }
      #pragma unroll
      for (int r = 0; r < 4; ++r)
        psum[wv][4 * g4 + r][col] = (acc0[r] + acc1[r]) * inv_s[4 * g4 + r];
    }
    SYNCL();
    {
      const int q = t >> 4, d = t & 15;
      float s = psum[0][q][d] + psum[1][q][d] + psum[2][q][d] + psum[3][q][d];
      const int b = bh >> 3, h = bh & 7;
      ctx_out[(size_t)(b * 2048 + q0 + q) * 128 + h * 16 + d] = s;
    }

    // ---- Phase C: normalized attn, sector-complete contiguous CACHED stores.
    // Zero loads exist after the prologue, so these L2-allocating stores
    // never collide with load traffic — the fill-kernel configuration.
    {
      float* arow = attn_out + ((size_t)bh * 2048 + q0) * 2048;
      const int c4 = t * 4;
      for (int q = 0; q < 16; ++q) {
        float inv = inv_s[q];
        short4v v0 = *(const short4v*)&sE[q][c4];
        short4v v1 = *(const short4v*)&sE[q][1024 + c4];
        f32x4 w0, w1;
        #pragma unroll
        for (int j = 0; j < 4; ++j) {
          w0[j] = bf2f(v0[j]) * inv;
          w1[j] = bf2f(v1[j]) * inv;
        }
        *(f32x4*)(arow + (size_t)q * 2048 + c4)        = w0;
        *(f32x4*)(arow + (size_t)q * 2048 + 1024 + c4) = w1;
      }
    }
    SYNCL();   // sE read-complete (lgkm only) before next tile overwrites it
  }
}

extern "C" void kernel_launch(void* const* d_in, const int* in_sizes, int n_in,
                              void* d_out, int out_size, void* d_ws, size_t ws_size,
                              hipStream_t stream) {
  const float* query = (const float*)d_in[0];
  const float* key   = (const float*)d_in[1];
  const float* value = (const float*)d_in[2];
  const float* Wq    = (const float*)d_in[3];
  const float* bq    = (const float*)d_in[4];
  const float* Wk    = (const float*)d_in[5];
  const float* bk    = (const float*)d_in[6];
  const float* Wv    = (const float*)d_in[7];
  const float* bv    = (const float*)d_in[8];
  const float* Wo    = (const float*)d_in[9];
  const float* bo    = (const float*)d_in[10];

  float* out  = (float*)d_out;
  float* attn = out + (size_t)8 * 2048 * 128;

  // ws: Wh f16 4x16384 | Q,K bf16 [64][2048][16] | V^T bf16 [64][16][2048] | ctx f32
  _Float16*       Wh  = (_Float16*)d_ws;
  __hip_bfloat16* Qw  = (__hip_bfloat16*)(Wh + 4 * 16384);
  __hip_bfloat16* Kw  = Qw + (size_t)64 * 2048 * 16;
  __hip_bfloat16* Vw  = Kw + (size_t)64 * 2048 * 16;
  float*          ctx = (float*)(Vw + (size_t)64 * 2048 * 16);

  dim3 blk(256);
  cvt_w_kernel<<<64, blk, 0, stream>>>(Wq, Wk, Wv, Wo, Wh);
  // Q prescale: 1/sqrt(D) * log2(e) so scores are base-2; softmax unchanged.
  proj16<0><<<256, blk, 0, stream>>>(query, Wh,             bq, Qw, 0.25f * 1.44269504f);
  proj16<0><<<256, blk, 0, stream>>>(key,   Wh + 16384,     bk, Kw, 1.0f);
  proj16<1><<<256, blk, 0, stream>>>(value, Wh + 2 * 16384, bv, Vw, 1.0f);
  attn_kernel<<<2048, blk, 0, stream>>>(Qw, Kw, Vw, attn, ctx);
  proj16<2><<<256, blk, 0, stream>>>(ctx,  Wh + 3 * 16384,  bo, out, 1.0f);
}

// Round 13
// 244.122 us; speedup vs baseline: 1.0790x; 1.0790x over previous
//
#include <hip/hip_runtime.h>
#include <hip/hip_bf16.h>

// B=8, S=2048, E=128, H=8, D=16;  BH=64;  N=B*S=16384
// R13 = exact revert to R8 (best measured: 244 us).
// Evidence chain: store-flavor x structure matrix fully explored R5-R12;
// nt + streamed 4-tile persistent + lgkm-only barriers is the optimum.

typedef __attribute__((ext_vector_type(4))) float f32x4;
typedef __attribute__((ext_vector_type(8))) short bf16x8;
typedef __attribute__((ext_vector_type(8))) _Float16 half8;
typedef __attribute__((ext_vector_type(2))) int int2v;
typedef __attribute__((ext_vector_type(4))) int int4v;
typedef __attribute__((ext_vector_type(4))) short short4v;

static __device__ inline float bf2f(short s) {
  union { unsigned u; float f; } x; x.u = ((unsigned)(unsigned short)s) << 16;
  return x.f;
}
static __device__ inline bf16x8 maskfrag(bf16x8 v, int msk) {
  union { bf16x8 s; int4v i; } u; u.s = v;
  u.i[0] &= msk; u.i[1] &= msk; u.i[2] &= msk; u.i[3] &= msk;
  return u.s;
}

// Raw workgroup barrier that drains ONLY lgkmcnt (LDS) — global stores
// stay in flight across it. All cross-wave deps in attn_kernel are LDS.
#define SYNCL()                                          \
  do {                                                   \
    __builtin_amdgcn_sched_barrier(0);                   \
    asm volatile("s_waitcnt lgkmcnt(0)" ::: "memory");   \
    __builtin_amdgcn_s_barrier();                        \
    __builtin_amdgcn_sched_barrier(0);                   \
  } while (0)

// ---------------- W fp32 -> f16 (one-time) ----------------
__global__ __launch_bounds__(256) void cvt_w_kernel(const float* __restrict__ Wq,
                                                    const float* __restrict__ Wk,
                                                    const float* __restrict__ Wv,
                                                    const float* __restrict__ Wo,
                                                    _Float16* __restrict__ out) {
  int i = blockIdx.x * 256 + threadIdx.x;      // grid 64 -> 16384
  out[i]             = (_Float16)Wq[i];
  out[16384 + i]     = (_Float16)Wk[i];
  out[2 * 16384 + i] = (_Float16)Wv[i];
  out[3 * 16384 + i] = (_Float16)Wo[i];
}

// ---------------- MFMA projection: out = (x @ W^T + b) * scale ----------------
// MODE 0: bf16 [BH][S][16] (Q/K)   MODE 1: bf16 [BH][16][S] (V^T)   MODE 2: f32 [N][128]
template <int MODE>
__global__ __launch_bounds__(256) void proj16(const float* __restrict__ x,
                                              const _Float16* __restrict__ Wh,
                                              const float* __restrict__ bias,
                                              void* __restrict__ out, float scale) {
  const int t = threadIdx.x;
  const int wv = t >> 6, lane = t & 63;
  const int col = lane & 15, g4 = lane >> 4;
  const int r0 = blockIdx.x * 64 + wv * 16;

  f32x4 acc[8];
  #pragma unroll
  for (int et = 0; et < 8; ++et) {
    float bv = bias[et * 16 + col];
    acc[et] = (f32x4){bv, bv, bv, bv};
  }
  #pragma unroll
  for (int ck = 0; ck < 4; ++ck) {
    const float* xp = x + (size_t)(r0 + col) * 128 + ck * 32 + g4 * 8;
    f32x4 x0 = *(const f32x4*)xp;
    f32x4 x1 = *(const f32x4*)(xp + 4);
    half8 a;
    #pragma unroll
    for (int j = 0; j < 4; ++j) { a[j] = (_Float16)x0[j]; a[j + 4] = (_Float16)x1[j]; }
    #pragma unroll
    for (int et = 0; et < 8; ++et) {
      half8 b = *(const half8*)(Wh + (size_t)(et * 16 + col) * 128 + ck * 32 + g4 * 8);
      acc[et] = __builtin_amdgcn_mfma_f32_16x16x32_f16(a, b, acc[et], 0, 0, 0);
    }
  }
  #pragma unroll
  for (int et = 0; et < 8; ++et) {
    #pragma unroll
    for (int rr = 0; rr < 4; ++rr) {
      int n = r0 + 4 * g4 + rr;
      float v = acc[et][rr] * scale;
      if (MODE == 2) {
        ((float*)out)[(size_t)n * 128 + et * 16 + col] = v;
      } else {
        int bb = n >> 11, s = n & 2047;
        size_t idx = (MODE == 0)
            ? ((size_t)(bb * 8 + et) * 2048 + s) * 16 + col
            : ((size_t)(bb * 8 + et) * 16 + col) * 2048 + s;
        ((__hip_bfloat16*)out)[idx] = __float2bfloat16(v);
      }
    }
  }
}

// ---------------- fused attention (persistent, 4 q-tiles per block) ----------
// grid: 64 heads * 32 groups; block 256 (4 waves); 4 tiles x 16 q-rows each.
// Qg,Kg: [BH][S][16] bf16 (Q pre-scaled 0.25*log2e); Vt: [BH][16][S] bf16.
// Per tile: A (QK^T -> exp2 -> LDS + sums) | b | inv | b | D (PV) | b |
//           ctx + C (sector-complete nt stores, fire-and-forget) | b |.
// Barriers are lgkmcnt-only (SYNCL): tile i's attn stores drain under
// tile i+1's compute. K is L2-reused across the 4 tiles.
__global__ __launch_bounds__(256) void attn_kernel(const __hip_bfloat16* __restrict__ Qg,
                                                   const __hip_bfloat16* __restrict__ Kg,
                                                   const __hip_bfloat16* __restrict__ Vt,
                                                   float* __restrict__ attn_out,
                                                   float* __restrict__ ctx_out) {
  __shared__ short sE[16][2056];     // bf16 2^(s'); +8 pad
  __shared__ float wsum[4][16];
  __shared__ float inv_s[16];
  __shared__ float psum[4][16][16];
  const int t = threadIdx.x;
  const int wv = t >> 6, lane = t & 63;
  const int col = lane & 15, g4 = lane >> 4;
  const int bh = blockIdx.x >> 5;
  const int qg = (blockIdx.x & 31) * 64;
  const int msk = (lane < 32) ? -1 : 0;

  const __hip_bfloat16* kp0 =
      Kg + ((size_t)bh * 2048 + (size_t)(wv * 32) * 16 + col) * 16 + (g4 & 1) * 8;
  const __hip_bfloat16* vp0 =
      Vt + ((size_t)bh * 16 + col) * 2048 + (size_t)(wv * 16) * 32 + 8 * g4;

  for (int tile = 0; tile < 4; ++tile) {
    const int q0 = qg + tile * 16;

    // ---- Phase A: S' = Q'K^T (base-2 scores), e = exp2(S') -> LDS + sums ----
    bf16x8 qfrag =
        *(const bf16x8*)(Qg + (((size_t)bh * 2048 + q0 + col) * 16 + (g4 & 1) * 8));
    const __hip_bfloat16* kp = kp0;
    float rsum = 0.f;

#define PROC_A(KF, KT)                                                              \
  {                                                                                 \
    f32x4 c = __builtin_amdgcn_mfma_f32_16x16x32_bf16(maskfrag((KF), msk), qfrag,   \
                                                      (f32x4){0.f, 0.f, 0.f, 0.f}, \
                                                      0, 0, 0);                     \
    float e0 = exp2f(c[0]), e1 = exp2f(c[1]);                                       \
    float e2 = exp2f(c[2]), e3 = exp2f(c[3]);                                       \
    rsum += (e0 + e1) + (e2 + e3);                                                  \
    union { __hip_bfloat162 h; int u; } p0, p1;                                     \
    p0.h = __float22bfloat162_rn(make_float2(e0, e1));                              \
    p1.h = __float22bfloat162_rn(make_float2(e2, e3));                              \
    int2v pk = {p0.u, p1.u};                                                        \
    *(int2v*)&sE[col][(KT) * 16 + 4 * g4] = pk;                                     \
  }

    bf16x8 kf0 = *(const bf16x8*)(kp);
    bf16x8 kf1 = *(const bf16x8*)(kp + 256);
    bf16x8 kf2 = *(const bf16x8*)(kp + 512);
    bf16x8 kf3 = *(const bf16x8*)(kp + 768);
    kp += 1024;
    for (int ib = 0; ib < 8; ++ib) {
      bf16x8 kn0 = *(const bf16x8*)(kp);
      bf16x8 kn1 = *(const bf16x8*)(kp + 256);
      bf16x8 kn2 = *(const bf16x8*)(kp + 512);
      bf16x8 kn3 = *(const bf16x8*)(kp + 768);
      kp += 1024;
      int ktb = wv * 32 + ib * 4;
      PROC_A(kf0, ktb + 0)
      PROC_A(kf1, ktb + 1)
      PROC_A(kf2, ktb + 2)
      PROC_A(kf3, ktb + 3)
      kf0 = kn0; kf1 = kn1; kf2 = kn2; kf3 = kn3;
    }
#undef PROC_A

    rsum += __shfl_xor(rsum, 16);
    rsum += __shfl_xor(rsum, 32);
    if (lane < 16) wsum[wv][lane] = rsum;
    SYNCL();
    if (t < 16) inv_s[t] = 1.f / (wsum[0][t] + wsum[1][t] + wsum[2][t] + wsum[3][t]);
    SYNCL();

    // ---- Phase D: ctx = P V (waves split K; prefetched V; dual acc) ----
    {
      const __hip_bfloat16* vp = vp0;
      const int kbb = (wv * 16) * 32 + 8 * g4;
      f32x4 acc0 = {0.f, 0.f, 0.f, 0.f}, acc1 = {0.f, 0.f, 0.f, 0.f};
      bf16x8 vf0 = *(const bf16x8*)(vp);
      bf16x8 vf1 = *(const bf16x8*)(vp + 32);
      bf16x8 vf2 = *(const bf16x8*)(vp + 64);
      bf16x8 vf3 = *(const bf16x8*)(vp + 96);
      vp += 128;
      #pragma unroll
      for (int ib = 0; ib < 4; ++ib) {
        bf16x8 vn0 = *(const bf16x8*)(vp);
        bf16x8 vn1 = *(const bf16x8*)(vp + 32);
        bf16x8 vn2 = *(const bf16x8*)(vp + 64);
        bf16x8 vn3 = *(const bf16x8*)(vp + 96);
        vp += 128;
        int kb = kbb + ib * 128;
        bf16x8 a0 = *(const bf16x8*)&sE[col][kb];
        acc0 = __builtin_amdgcn_mfma_f32_16x16x32_bf16(a0, vf0, acc0, 0, 0, 0);
        bf16x8 a1 = *(const bf16x8*)&sE[col][kb + 32];
        acc1 = __builtin_amdgcn_mfma_f32_16x16x32_bf16(a1, vf1, acc1, 0, 0, 0);
        bf16x8 a2 = *(const bf16x8*)&sE[col][kb + 64];
        acc0 = __builtin_amdgcn_mfma_f32_16x16x32_bf16(a2, vf2, acc0, 0, 0, 0);
        bf16x8 a3 = *(const bf16x8*)&sE[col][kb + 96];
        acc1 = __builtin_amdgcn_mfma_f32_16x16x32_bf16(a3, vf3, acc1, 0, 0, 0);
        vf0 = vn0; vf1 = vn1; vf2 = vn2; vf3 = vn3;
      }
      #pragma unroll
      for (int r = 0; r < 4; ++r)
        psum[wv][4 * g4 + r][col] = (acc0[r] + acc1[r]) * inv_s[4 * g4 + r];
    }
    SYNCL();
    {
      const int q = t >> 4, d = t & 15;
      float s = psum[0][q][d] + psum[1][q][d] + psum[2][q][d] + psum[3][q][d];
      const int b = bh >> 3, h = bh & 7;
      ctx_out[(size_t)(b * 2048 + q0 + q) * 128 + h * 16 + d] = s;
    }

    // ---- Phase C: normalized attn, sector-complete contiguous nt stores.
    // Fire-and-forget: next tile's barriers are lgkm-only, so these drain
    // under tile+1's Phase A compute.
    {
      float* arow = attn_out + ((size_t)bh * 2048 + q0) * 2048;
      const int c4 = t * 4;
      for (int q = 0; q < 16; ++q) {
        float inv = inv_s[q];
        short4v v0 = *(const short4v*)&sE[q][c4];
        short4v v1 = *(const short4v*)&sE[q][1024 + c4];
        f32x4 w0, w1;
        #pragma unroll
        for (int j = 0; j < 4; ++j) {
          w0[j] = bf2f(v0[j]) * inv;
          w1[j] = bf2f(v1[j]) * inv;
        }
        __builtin_nontemporal_store(w0, (f32x4*)(arow + (size_t)q * 2048 + c4));
        __builtin_nontemporal_store(w1, (f32x4*)(arow + (size_t)q * 2048 + 1024 + c4));
      }
    }
    SYNCL();   // sE read-complete (lgkm only) before next tile overwrites it
  }
}

extern "C" void kernel_launch(void* const* d_in, const int* in_sizes, int n_in,
                              void* d_out, int out_size, void* d_ws, size_t ws_size,
                              hipStream_t stream) {
  const float* query = (const float*)d_in[0];
  const float* key   = (const float*)d_in[1];
  const float* value = (const float*)d_in[2];
  const float* Wq    = (const float*)d_in[3];
  const float* bq    = (const float*)d_in[4];
  const float* Wk    = (const float*)d_in[5];
  const float* bk    = (const float*)d_in[6];
  const float* Wv    = (const float*)d_in[7];
  const float* bv    = (const float*)d_in[8];
  const float* Wo    = (const float*)d_in[9];
  const float* bo    = (const float*)d_in[10];

  float* out  = (float*)d_out;
  float* attn = out + (size_t)8 * 2048 * 128;

  // ws: Wh f16 4x16384 | Q,K bf16 [64][2048][16] | V^T bf16 [64][16][2048] | ctx f32
  _Float16*       Wh  = (_Float16*)d_ws;
  __hip_bfloat16* Qw  = (__hip_bfloat16*)(Wh + 4 * 16384);
  __hip_bfloat16* Kw  = Qw + (size_t)64 * 2048 * 16;
  __hip_bfloat16* Vw  = Kw + (size_t)64 * 2048 * 16;
  float*          ctx = (float*)(Vw + (size_t)64 * 2048 * 16);

  dim3 blk(256);
  cvt_w_kernel<<<64, blk, 0, stream>>>(Wq, Wk, Wv, Wo, Wh);
  // Q prescale: 1/sqrt(D) * log2(e) so scores are base-2; softmax unchanged.
  proj16<0><<<256, blk, 0, stream>>>(query, Wh,             bq, Qw, 0.25f * 1.44269504f);
  proj16<0><<<256, blk, 0, stream>>>(key,   Wh + 16384,     bk, Kw, 1.0f);
  proj16<1><<<256, blk, 0, stream>>>(value, Wh + 2 * 16384, bv, Vw, 1.0f);
  attn_kernel<<<2048, blk, 0, stream>>>(Qw, Kw, Vw, attn, ctx);
  proj16<2><<<256, blk, 0, stream>>>(ctx,  Wh + 3 * 16384,  bo, out, 1.0f);
}